// Round 1
// baseline (968.644 us; speedup 1.0000x reference)
//
#include <hip/hip_runtime.h>
#include <type_traits>
#include <utility>

typedef unsigned short u16;
typedef __attribute__((ext_vector_type(8))) short short8;
typedef __attribute__((ext_vector_type(8))) __bf16 bf16v8;
typedef __attribute__((ext_vector_type(4))) float f32x4;

// gfx950 mfma_f32_16x16x32_bf16 signature hedge: pick whichever vector type the
// builtin accepts (V8y __bf16 per LLVM, short8 per guide examples).
template <typename T, typename = void> struct mfma_ok : std::false_type {};
template <typename T>
struct mfma_ok<T, std::void_t<decltype(__builtin_amdgcn_mfma_f32_16x16x32_bf16(
    std::declval<T>(), std::declval<T>(), std::declval<f32x4>(), 0, 0, 0))>>
    : std::true_type {};
using frag8 = std::conditional_t<mfma_ok<bf16v8>::value, bf16v8, short8>;

#define MFMA16(a, b, c) __builtin_amdgcn_mfma_f32_16x16x32_bf16((a), (b), (c), 0, 0, 0)

__device__ __forceinline__ float bf2f(u16 u) {
  unsigned v = ((unsigned)u) << 16;
  return __builtin_bit_cast(float, v);
}
__device__ __forceinline__ u16 f2bf(float f) {
  unsigned u = __builtin_bit_cast(unsigned, f);
  u = (u + 0x7fffu + ((u >> 16) & 1u)) >> 16;
  return (u16)u;
}

// ---------------------------------------------------------------- score
// entropy over 4 channels, 8x8 box filter stride 4 -> 225 scores per batch
__global__ void k_score(const float* __restrict__ prob, const float* __restrict__ wfix,
                        float* __restrict__ scores) {
  const int b = blockIdx.x, tid = threadIdx.x;
  __shared__ float ent[64 * 64];
  __shared__ float wf[64];
  if (tid < 64) wf[tid] = wfix[tid];
  const float* pb = prob + (size_t)b * 4 * 4096;
  for (int p = tid; p < 4096; p += 256) {
    float e = 0.f;
#pragma unroll
    for (int ch = 0; ch < 4; ++ch) {
      float v = pb[ch * 4096 + p];
      e -= v * log2f(v + 1e-10f);
    }
    ent[p] = e;
  }
  __syncthreads();
  if (tid < 225) {
    int wy = tid / 15, wx = tid % 15;
    float s = 0.f;
    for (int a = 0; a < 8; ++a)
      for (int c = 0; c < 8; ++c)
        s += ent[(wy * 4 + a) * 64 + wx * 4 + c] * wf[a * 8 + c];
    scores[b * 225 + tid] = s * (1.0f / 64.0f);
  }
}

// ---------------------------------------------------------------- nms
__device__ __forceinline__ float iou_pair(int wa, int wb) {
  float x1a = (float)((wa % 15) * 8), y1a = (float)((wa / 15) * 8);
  float x1b = (float)((wb % 15) * 8), y1b = (float)((wb / 15) * 8);
  float iw = fminf(x1a, x1b) + 15.f - fmaxf(x1a, x1b);
  float ih = fminf(y1a, y1b) + 15.f - fmaxf(y1a, y1b);
  iw = fmaxf(iw, 0.f);
  ih = fmaxf(ih, 0.f);
  float inter = iw * ih;
  return inter / (450.f - inter);
}

__global__ void k_nms(const float* __restrict__ scores, int* __restrict__ sel,
                      int* __restrict__ kept, float* __restrict__ mult) {
  const int b = blockIdx.x, t = threadIdx.x;
  __shared__ float s[225];
  __shared__ int order[225];
  __shared__ unsigned char supp[225];
  __shared__ int idx44[44];
  __shared__ int ks[225];
  __shared__ float ml[225];
  if (t < 225) s[t] = scores[b * 225 + t];
  __syncthreads();
  if (t < 225) {
    float st = s[t];
    int r = 0;
    for (int j = 0; j < 225; ++j) {
      float sj = s[j];
      r += (sj > st) || (sj == st && j < t);  // stable descending rank
    }
    order[r] = t;
    supp[t] = 0;
    ks[t] = -1;
    ml[t] = 0.f;
  }
  __syncthreads();
  for (int i = 0; i < 224; ++i) {
    if (t > i && t < 225 && !supp[i]) {
      if (iou_pair(order[i], order[t]) > 0.2f) supp[t] = 1;
    }
    __syncthreads();
  }
  if (t == 0) {
    int k = 0;
    for (int i = 0; i < 225 && k < 44; ++i)
      if (!supp[i]) idx44[k++] = order[i];
    while (k < 44) idx44[k++] = order[224];  // reference pad: order[M-1]
    for (int k2 = 0; k2 < 44; ++k2) {
      int w = idx44[k2];
      if (ks[w] < 0) ks[w] = k2;
      ml[w] += 1.f;
    }
  }
  __syncthreads();
  if (t < 225) {
    kept[b * 225 + t] = ks[t];
    mult[b * 225 + t] = ml[t];
  }
  if (t < 44) sel[b * 44 + t] = idx44[t];
}

// ---------------------------------------------------------------- weight cast
__global__ void k_castw(const float* __restrict__ Wq, const float* __restrict__ Wo,
                        u16* __restrict__ wqb, u16* __restrict__ wob) {
  int idx = blockIdx.x * 256 + threadIdx.x;
  if (idx < 786432) wqb[idx] = f2bf(Wq[idx]);
  int i2 = idx - 786432;
  if (i2 >= 0 && i2 < 262144) wob[i2] = f2bf(Wo[i2]);
}

// ---------------------------------------------------------------- gather + bilinear
// xi[g][p*16+q][d] = sum_ij A[p][i] * x2d[b][d][sy+i][sx+j] * A[q][j]
__global__ void k_gather(const float* __restrict__ x, const int* __restrict__ sel,
                         u16* __restrict__ xi) {
  const int g = blockIdx.x;  // b*44 + slot
  const int b = g / 44;
  const int tid = threadIdx.x;
  const int w = sel[g];
  const int sy = (w / 15) * 8, sx = (w % 15) * 8;
  __shared__ float A16[16][16];
  __shared__ float Pch[256][32];
  __shared__ float Tch[256][32];
  if (tid < 16) {
#pragma unroll
    for (int q = 0; q < 16; ++q) A16[tid][q] = 0.f;
    float r = (tid + 0.5f) * 0.9375f;  // exact in f32
    int q0 = (int)r;
    float f = r - (float)q0;
    A16[tid][q0] = 1.0f - f;
    int q1 = q0 + 1 > 15 ? 15 : q0 + 1;
    A16[tid][q1] += f;
  }
  const float* xb = x + (size_t)b * 16384 * 512;
  __syncthreads();
  for (int d0 = 0; d0 < 512; d0 += 32) {
    for (int e = tid; e < 8192; e += 256) {
      int pix = e >> 5, dd = e & 31;
      int i = pix >> 4, j = pix & 15;
      Pch[pix][dd] = xb[((size_t)((sy + i) * 128 + sx + j)) * 512 + d0 + dd];
    }
    __syncthreads();
    for (int e = tid; e < 8192; e += 256) {
      int iq = e >> 5, dd = e & 31;
      int i = iq >> 4, q = iq & 15;
      float sacc = 0.f;
#pragma unroll
      for (int j = 0; j < 16; ++j) sacc += A16[q][j] * Pch[i * 16 + j][dd];
      Tch[iq][dd] = sacc;
    }
    __syncthreads();
    for (int e = tid; e < 8192; e += 256) {
      int pq = e >> 5, dd = e & 31;
      int p = pq >> 4, q = pq & 15;
      float sacc = 0.f;
#pragma unroll
      for (int i = 0; i < 16; ++i) sacc += A16[p][i] * Tch[i * 16 + q][dd];
      xi[((size_t)g * 256 + pq) * 512 + d0 + dd] = f2bf(sacc);
    }
    __syncthreads();
  }
}

// ---------------------------------------------------------------- GEMM  C = A * B^T (+bias)
// A[M][K] bf16 row-major, B[N][K] bf16 row-major, C[M][N] bf16. 128x128 tile, BK=32.
#define LDA_P 40
template <int BIAS>
__global__ __launch_bounds__(256) void k_gemm(const u16* __restrict__ A, const u16* __restrict__ B,
                                              u16* __restrict__ C, const float* __restrict__ bias,
                                              int M, int N, int K) {
  __shared__ u16 sA[128 * LDA_P];
  __shared__ u16 sB[128 * LDA_P];
  const int tid = threadIdx.x;
  const int lane = tid & 63;
  const int wv = tid >> 6;
  const int bn = blockIdx.x, bm = blockIdx.y;
  const int wm = (wv >> 1) * 64, wn = (wv & 1) * 64;
  const int r = tid >> 2, ko = (tid & 3) * 8;
  const size_t abase = (size_t)(bm * 128) * K;
  const size_t bbase = (size_t)(bn * 128) * K;
  f32x4 acc[4][4] = {};
  const int rowa = wm + (lane & 15);
  const int rowb = wn + (lane & 15);
  const int kk8 = (lane >> 4) * 8;
  for (int kt = 0; kt < K; kt += 32) {
    short8 va0 = *(const short8*)(A + abase + (size_t)r * K + kt + ko);
    short8 va1 = *(const short8*)(A + abase + (size_t)(r + 64) * K + kt + ko);
    short8 vb0 = *(const short8*)(B + bbase + (size_t)r * K + kt + ko);
    short8 vb1 = *(const short8*)(B + bbase + (size_t)(r + 64) * K + kt + ko);
    __syncthreads();  // previous iteration's reads complete
    *(short8*)&sA[r * LDA_P + ko] = va0;
    *(short8*)&sA[(r + 64) * LDA_P + ko] = va1;
    *(short8*)&sB[r * LDA_P + ko] = vb0;
    *(short8*)&sB[(r + 64) * LDA_P + ko] = vb1;
    __syncthreads();
    frag8 af[4], bf[4];
#pragma unroll
    for (int i = 0; i < 4; ++i) af[i] = *(const frag8*)&sA[(rowa + i * 16) * LDA_P + kk8];
#pragma unroll
    for (int i = 0; i < 4; ++i) bf[i] = *(const frag8*)&sB[(rowb + i * 16) * LDA_P + kk8];
#pragma unroll
    for (int i = 0; i < 4; ++i)
#pragma unroll
      for (int j = 0; j < 4; ++j) acc[i][j] = MFMA16(af[i], bf[j], acc[i][j]);
  }
  const int c0 = lane & 15, r0 = (lane >> 4) * 4;
#pragma unroll
  for (int i = 0; i < 4; ++i)
#pragma unroll
    for (int j = 0; j < 4; ++j)
#pragma unroll
      for (int e = 0; e < 4; ++e) {
        int row = bm * 128 + wm + i * 16 + r0 + e;
        int col = bn * 128 + wn + j * 16 + c0;
        float v = acc[i][j][e];
        if (BIAS) v += bias[col];
        C[(size_t)row * N + col] = f2bf(v);
      }
}

// ---------------------------------------------------------------- attention
// one workgroup per (window, head); 4 waves, each owns 64 q-rows; flash-style online softmax
__global__ __launch_bounds__(256, 1) void k_attn(const u16* __restrict__ qkv,
                                                 u16* __restrict__ aout) {
  const int g = blockIdx.x;
  const int win = g >> 3, h = g & 7;
  const int tid = threadIdx.x, lane = tid & 63, wv = tid >> 6;
  __shared__ u16 Ks[256][72];
  __shared__ u16 Vt[64][264];
  __shared__ u16 Ps[4][64][72];
  const u16* base = qkv + (size_t)win * 256 * 1536;
  // K tile [256 keys][64 d], padded
  for (int e = tid; e < 2048; e += 256) {
    int row = e >> 3, c8 = (e & 7) * 8;
    *(short8*)&Ks[row][c8] = *(const short8*)(base + (size_t)row * 1536 + 512 + h * 64 + c8);
  }
  // V transposed: Vt[d][key]
  {
    const u16* vp = base + (size_t)tid * 1536 + 1024 + h * 64;
#pragma unroll
    for (int c8 = 0; c8 < 64; c8 += 8) {
      short8 v = *(const short8*)(vp + c8);
#pragma unroll
      for (int e2 = 0; e2 < 8; ++e2) Vt[c8 + e2][tid] = (u16)v[e2];
    }
  }
  // Q fragments (held in registers for all 4 key-blocks)
  frag8 qf[4][2];
#pragma unroll
  for (int mf = 0; mf < 4; ++mf)
#pragma unroll
    for (int kk = 0; kk < 2; ++kk)
      qf[mf][kk] = *(const frag8*)(base + (size_t)(wv * 64 + mf * 16 + (lane & 15)) * 1536 +
                                   h * 64 + kk * 32 + (lane >> 4) * 8);
  __syncthreads();

  float m_run[4][4], l_run[4][4];
  f32x4 of[4][4];
#pragma unroll
  for (int mf = 0; mf < 4; ++mf)
#pragma unroll
    for (int j = 0; j < 4; ++j) {
      m_run[mf][j] = -3e38f;
      l_run[mf][j] = 0.f;
    }
#pragma unroll
  for (int mf = 0; mf < 4; ++mf)
#pragma unroll
    for (int df = 0; df < 4; ++df) of[mf][df] = 0.f;

  u16(*Pw)[72] = Ps[wv];
  for (int kb = 0; kb < 4; ++kb) {
    f32x4 sf[4][4] = {};
#pragma unroll
    for (int kk = 0; kk < 2; ++kk) {
      frag8 kf[4];
#pragma unroll
      for (int nf = 0; nf < 4; ++nf)
        kf[nf] = *(const frag8*)&Ks[kb * 64 + nf * 16 + (lane & 15)][kk * 32 + (lane >> 4) * 8];
#pragma unroll
      for (int mf = 0; mf < 4; ++mf)
#pragma unroll
        for (int nf = 0; nf < 4; ++nf) sf[mf][nf] = MFMA16(qf[mf][kk], kf[nf], sf[mf][nf]);
    }
#pragma unroll
    for (int mf = 0; mf < 4; ++mf)
#pragma unroll
      for (int nf = 0; nf < 4; ++nf) sf[mf][nf] *= 0.125f;  // SCALE
    // online softmax per owned row (mf, j)
#pragma unroll
    for (int mf = 0; mf < 4; ++mf) {
#pragma unroll
      for (int j = 0; j < 4; ++j) {
        float bm = fmaxf(fmaxf(sf[mf][0][j], sf[mf][1][j]), fmaxf(sf[mf][2][j], sf[mf][3][j]));
        bm = fmaxf(bm, __shfl_xor(bm, 1));
        bm = fmaxf(bm, __shfl_xor(bm, 2));
        bm = fmaxf(bm, __shfl_xor(bm, 4));
        bm = fmaxf(bm, __shfl_xor(bm, 8));
        float mo = m_run[mf][j];
        float mn = fmaxf(mo, bm);
        float corr = __expf(mo - mn);
        m_run[mf][j] = mn;
        float rs = 0.f;
#pragma unroll
        for (int nf = 0; nf < 4; ++nf) {
          float p = __expf(sf[mf][nf][j] - mn);
          sf[mf][nf][j] = p;
          rs += p;
        }
        rs += __shfl_xor(rs, 1);
        rs += __shfl_xor(rs, 2);
        rs += __shfl_xor(rs, 4);
        rs += __shfl_xor(rs, 8);
        l_run[mf][j] = l_run[mf][j] * corr + rs;
#pragma unroll
        for (int df = 0; df < 4; ++df) of[mf][df][j] *= corr;
      }
    }
    // stage P (bf16) into per-wave LDS in A-fragment layout
#pragma unroll
    for (int mf = 0; mf < 4; ++mf)
#pragma unroll
      for (int nf = 0; nf < 4; ++nf)
#pragma unroll
        for (int j = 0; j < 4; ++j)
          Pw[mf * 16 + (lane >> 4) * 4 + j][nf * 16 + (lane & 15)] = f2bf(sf[mf][nf][j]);
    asm volatile("" ::: "memory");  // keep compiler from reordering LDS r/w (HW is in-order per wave)
    // O += P @ V
#pragma unroll
    for (int kk = 0; kk < 2; ++kk) {
      frag8 pa[4], vb[4];
#pragma unroll
      for (int mf = 0; mf < 4; ++mf)
        pa[mf] = *(const frag8*)&Pw[mf * 16 + (lane & 15)][kk * 32 + (lane >> 4) * 8];
#pragma unroll
      for (int df = 0; df < 4; ++df)
        vb[df] = *(const frag8*)&Vt[df * 16 + (lane & 15)][kb * 64 + kk * 32 + (lane >> 4) * 8];
#pragma unroll
      for (int mf = 0; mf < 4; ++mf)
#pragma unroll
        for (int df = 0; df < 4; ++df) of[mf][df] = MFMA16(pa[mf], vb[df], of[mf][df]);
    }
    asm volatile("" ::: "memory");
  }
  // epilogue: normalize and store
#pragma unroll
  for (int mf = 0; mf < 4; ++mf)
#pragma unroll
    for (int df = 0; df < 4; ++df)
#pragma unroll
      for (int j = 0; j < 4; ++j) {
        int row = win * 256 + wv * 64 + mf * 16 + (lane >> 4) * 4 + j;
        int col = h * 64 + df * 16 + (lane & 15);
        aout[(size_t)row * 512 + col] = f2bf(of[mf][df][j] / l_run[mf][j]);
      }
}

// ---------------------------------------------------------------- finalize
// out[b][pix][d] = x + sum(covering kept windows)/(cnt+1e-10)
__global__ void k_final(const float* __restrict__ x, const u16* __restrict__ proj,
                        const int* __restrict__ kept, const float* __restrict__ mult,
                        float* __restrict__ out) {
  const size_t idx = (size_t)blockIdx.x * 256 + threadIdx.x;
  const int dci = (int)(idx & 31);
  const int pix = (int)((idx >> 5) & 16383);
  const int b = (int)(idx >> 19);
  const int y = pix >> 7, xc = pix & 127;
  float acc[16];
#pragma unroll
  for (int e = 0; e < 16; ++e) acc[e] = 0.f;
  float c = 0.f;
  const int wyh = y >> 3, wxh = xc >> 3;
#pragma unroll
  for (int a = 0; a < 2; ++a) {
    int wy = wyh - 1 + a;
    if (wy < 0 || wy > 14) continue;
#pragma unroll
    for (int bb = 0; bb < 2; ++bb) {
      int wx = wxh - 1 + bb;
      if (wx < 0 || wx > 14) continue;
      int w = wy * 15 + wx;
      int slot = kept[b * 225 + w];
      if (slot < 0) continue;
      float ml = mult[b * 225 + w];
      c += ml;
      const u16* pr = proj +
                      ((size_t)((b * 44 + slot) * 256 + (y - wy * 8) * 16 + (xc - wx * 8))) * 512 +
                      (size_t)dci * 16;
      short8 v0 = *(const short8*)pr;
      short8 v1 = *(const short8*)(pr + 8);
#pragma unroll
      for (int e = 0; e < 8; ++e) acc[e] += ml * bf2f((u16)v0[e]);
#pragma unroll
      for (int e = 0; e < 8; ++e) acc[8 + e] += ml * bf2f((u16)v1[e]);
    }
  }
  const float inv = 1.f / (c + 1e-10f);
  const size_t off = ((size_t)(b * 16384 + pix)) * 512 + (size_t)dci * 16;
  const float4* xp = (const float4*)(x + off);
  float4* op = (float4*)(out + off);
#pragma unroll
  for (int q4 = 0; q4 < 4; ++q4) {
    float4 xv = xp[q4];
    float4 ov;
    ov.x = xv.x + acc[q4 * 4 + 0] * inv;
    ov.y = xv.y + acc[q4 * 4 + 1] * inv;
    ov.z = xv.z + acc[q4 * 4 + 2] * inv;
    ov.w = xv.w + acc[q4 * 4 + 3] * inv;
    op[q4] = ov;
  }
}

// ---------------------------------------------------------------- launch
extern "C" void kernel_launch(void* const* d_in, const int* in_sizes, int n_in, void* d_out,
                              int out_size, void* d_ws, size_t ws_size, hipStream_t stream) {
  const float* x = (const float*)d_in[0];
  const float* prob = (const float*)d_in[1];
  const float* wfix = (const float*)d_in[2];
  const float* Wq = (const float*)d_in[3];
  const float* Wo = (const float*)d_in[4];
  const float* bo = (const float*)d_in[5];
  float* out = (float*)d_out;
  char* ws = (char*)d_ws;

  float* scores = (float*)(ws + 0);           // 7200 B
  int* sel = (int*)(ws + 8192);               // 1408 B
  int* kept = (int*)(ws + 16384);             // 7200 B
  float* mult = (float*)(ws + 24576);         // 7200 B
  u16* wqb = (u16*)(ws + 32768);              // 1,572,864 B
  u16* wob = (u16*)(ws + 32768 + 1572864);    // 524,288 B
  u16* xi = (u16*)(ws + 4194304);             // 92,274,688 B (reused as attn output)
  u16* qkv = (u16*)(ws + 4194304 + 92274688); // 276,824,064 B (reused as proj output)
  u16* aout = xi;
  u16* proj = qkv;

  k_score<<<8, 256, 0, stream>>>(prob, wfix, scores);
  k_nms<<<8, 256, 0, stream>>>(scores, sel, kept, mult);
  k_castw<<<4096, 256, 0, stream>>>(Wq, Wo, wqb, wob);
  k_gather<<<352, 256, 0, stream>>>(x, sel, xi);
  k_gemm<0><<<dim3(12, 704), 256, 0, stream>>>(xi, wqb, qkv, nullptr, 90112, 1536, 512);
  k_attn<<<2816, 256, 0, stream>>>(qkv, aout);
  k_gemm<1><<<dim3(4, 704), 256, 0, stream>>>(aout, wob, proj, bo, 90112, 512, 512);
  k_final<<<16384, 256, 0, stream>>>(x, proj, kept, mult, out);
}

// Round 2
// 947.152 us; speedup vs baseline: 1.0227x; 1.0227x over previous
//
#include <hip/hip_runtime.h>
#include <type_traits>
#include <utility>

typedef unsigned short u16;
typedef __attribute__((ext_vector_type(8))) short short8;
typedef __attribute__((ext_vector_type(8))) __bf16 bf16v8;
typedef __attribute__((ext_vector_type(4))) float f32x4;

template <typename T, typename = void> struct mfma_ok : std::false_type {};
template <typename T>
struct mfma_ok<T, std::void_t<decltype(__builtin_amdgcn_mfma_f32_16x16x32_bf16(
    std::declval<T>(), std::declval<T>(), std::declval<f32x4>(), 0, 0, 0))>>
    : std::true_type {};
using frag8 = std::conditional_t<mfma_ok<bf16v8>::value, bf16v8, short8>;

#define MFMA16(a, b, c) __builtin_amdgcn_mfma_f32_16x16x32_bf16((a), (b), (c), 0, 0, 0)

__device__ __forceinline__ float bf2f(u16 u) {
  unsigned v = ((unsigned)u) << 16;
  return __builtin_bit_cast(float, v);
}
__device__ __forceinline__ u16 f2bf(float f) {
  unsigned u = __builtin_bit_cast(unsigned, f);
  u = (u + 0x7fffu + ((u >> 16) & 1u)) >> 16;
  return (u16)u;
}
__device__ __forceinline__ unsigned cvtpk_bf16(float lo, float hi) {
  unsigned r;
  asm("v_cvt_pk_bf16_f32 %0, %1, %2" : "=v"(r) : "v"(lo), "v"(hi));
  return r;
}
// async global->LDS, 16B per lane; lds ptr must be wave-uniform base (+lane*16 implicit)
__device__ __forceinline__ void gl16(const u16* g, u16* l) {
  __builtin_amdgcn_global_load_lds((__attribute__((address_space(1))) void*)(g),
                                   (__attribute__((address_space(3))) void*)(l), 16, 0, 0);
}

// ---------------------------------------------------------------- score
__global__ void k_score(const float* __restrict__ prob, const float* __restrict__ wfix,
                        float* __restrict__ scores) {
  const int b = blockIdx.x, tid = threadIdx.x;
  __shared__ float ent[64 * 64];
  __shared__ float wf[64];
  if (tid < 64) wf[tid] = wfix[tid];
  const float* pb = prob + (size_t)b * 4 * 4096;
  for (int p = tid; p < 4096; p += 256) {
    float e = 0.f;
#pragma unroll
    for (int ch = 0; ch < 4; ++ch) {
      float v = pb[ch * 4096 + p];
      e -= v * log2f(v + 1e-10f);
    }
    ent[p] = e;
  }
  __syncthreads();
  if (tid < 225) {
    int wy = tid / 15, wx = tid % 15;
    float s = 0.f;
    for (int a = 0; a < 8; ++a)
      for (int c = 0; c < 8; ++c)
        s += ent[(wy * 4 + a) * 64 + wx * 4 + c] * wf[a * 8 + c];
    scores[b * 225 + tid] = s * (1.0f / 64.0f);
  }
}

// ---------------------------------------------------------------- nms
__device__ __forceinline__ float iou_pair(int wa, int wb) {
  float x1a = (float)((wa % 15) * 8), y1a = (float)((wa / 15) * 8);
  float x1b = (float)((wb % 15) * 8), y1b = (float)((wb / 15) * 8);
  float iw = fminf(x1a, x1b) + 15.f - fmaxf(x1a, x1b);
  float ih = fminf(y1a, y1b) + 15.f - fmaxf(y1a, y1b);
  iw = fmaxf(iw, 0.f);
  ih = fmaxf(ih, 0.f);
  float inter = iw * ih;
  return inter / (450.f - inter);
}

__global__ void k_nms(const float* __restrict__ scores, int* __restrict__ sel,
                      int* __restrict__ kept, float* __restrict__ mult) {
  const int b = blockIdx.x, t = threadIdx.x;
  __shared__ float s[225];
  __shared__ int order[225];
  __shared__ unsigned char supp[225];
  __shared__ int idx44[44];
  __shared__ int ks[225];
  __shared__ float ml[225];
  if (t < 225) s[t] = scores[b * 225 + t];
  __syncthreads();
  if (t < 225) {
    float st = s[t];
    int r = 0;
    for (int j = 0; j < 225; ++j) {
      float sj = s[j];
      r += (sj > st) || (sj == st && j < t);
    }
    order[r] = t;
    supp[t] = 0;
    ks[t] = -1;
    ml[t] = 0.f;
  }
  __syncthreads();
  for (int i = 0; i < 224; ++i) {
    if (t > i && t < 225 && !supp[i]) {
      if (iou_pair(order[i], order[t]) > 0.2f) supp[t] = 1;
    }
    __syncthreads();
  }
  if (t == 0) {
    int k = 0;
    for (int i = 0; i < 225 && k < 44; ++i)
      if (!supp[i]) idx44[k++] = order[i];
    while (k < 44) idx44[k++] = order[224];
    for (int k2 = 0; k2 < 44; ++k2) {
      int w = idx44[k2];
      if (ks[w] < 0) ks[w] = k2;
      ml[w] += 1.f;
    }
  }
  __syncthreads();
  if (t < 225) {
    kept[b * 225 + t] = ks[t];
    mult[b * 225 + t] = ml[t];
  }
  if (t < 44) sel[b * 44 + t] = idx44[t];
}

// ---------------------------------------------------------------- weight cast
__global__ void k_castw(const float* __restrict__ Wq, const float* __restrict__ Wo,
                        u16* __restrict__ wqb, u16* __restrict__ wob) {
  int idx = blockIdx.x * 256 + threadIdx.x;
  if (idx < 786432) wqb[idx] = f2bf(Wq[idx]);
  int i2 = idx - 786432;
  if (i2 >= 0 && i2 < 262144) wob[i2] = f2bf(Wo[i2]);
}

// ---------------------------------------------------------------- gather + bilinear
__global__ void k_gather(const float* __restrict__ x, const int* __restrict__ sel,
                         u16* __restrict__ xi) {
  const int g = blockIdx.x;
  const int b = g / 44;
  const int tid = threadIdx.x;
  const int w = sel[g];
  const int sy = (w / 15) * 8, sx = (w % 15) * 8;
  __shared__ float A16[16][16];
  __shared__ float Pch[256][32];
  __shared__ float Tch[256][32];
  if (tid < 16) {
#pragma unroll
    for (int q = 0; q < 16; ++q) A16[tid][q] = 0.f;
    float r = (tid + 0.5f) * 0.9375f;
    int q0 = (int)r;
    float f = r - (float)q0;
    A16[tid][q0] = 1.0f - f;
    int q1 = q0 + 1 > 15 ? 15 : q0 + 1;
    A16[tid][q1] += f;
  }
  const float* xb = x + (size_t)b * 16384 * 512;
  __syncthreads();
  for (int d0 = 0; d0 < 512; d0 += 32) {
    for (int e = tid; e < 8192; e += 256) {
      int pix = e >> 5, dd = e & 31;
      int i = pix >> 4, j = pix & 15;
      Pch[pix][dd] = xb[((size_t)((sy + i) * 128 + sx + j)) * 512 + d0 + dd];
    }
    __syncthreads();
    for (int e = tid; e < 8192; e += 256) {
      int iq = e >> 5, dd = e & 31;
      int i = iq >> 4, q = iq & 15;
      float sacc = 0.f;
#pragma unroll
      for (int j = 0; j < 16; ++j) sacc += A16[q][j] * Pch[i * 16 + j][dd];
      Tch[iq][dd] = sacc;
    }
    __syncthreads();
    for (int e = tid; e < 8192; e += 256) {
      int pq = e >> 5, dd = e & 31;
      int p = pq >> 4, q = pq & 15;
      float sacc = 0.f;
#pragma unroll
      for (int i = 0; i < 16; ++i) sacc += A16[p][i] * Tch[i * 16 + q][dd];
      xi[((size_t)g * 256 + pq) * 512 + d0 + dd] = f2bf(sacc);
    }
    __syncthreads();
  }
}

// ---------------------------------------------------------------- GEMM  C = A * B^T (+bias)
// m97 structure: global_load_lds width-16, linear LDS [128][32], 2 barriers per K-step.
template <int BIAS>
__global__ __launch_bounds__(256) void k_gemm(const u16* __restrict__ A, const u16* __restrict__ B,
                                              u16* __restrict__ C, const float* __restrict__ bias,
                                              int M, int N, int K) {
  __shared__ u16 sA[128 * 32];
  __shared__ u16 sB[128 * 32];
  const int tid = threadIdx.x, lane = tid & 63, wv = tid >> 6;
  const int bn = blockIdx.x, bm = blockIdx.y;
  const int wm = (wv >> 1) * 64, wn = (wv & 1) * 64;
  // staging: wave wv covers tile bytes [wv*2048, wv*2048+2048) in two 1024B wave-instrs
  const int lb0 = wv * 2048, lb1 = wv * 2048 + 1024;
  const int gb0 = lb0 + lane * 16, gb1 = lb1 + lane * 16;
  const int r0 = gb0 >> 6, c0 = (gb0 & 63) >> 1;
  const int r1 = gb1 >> 6, c1 = (gb1 & 63) >> 1;
  const u16* Ag0 = A + (size_t)(bm * 128 + r0) * K + c0;
  const u16* Ag1 = A + (size_t)(bm * 128 + r1) * K + c1;
  const u16* Bg0 = B + (size_t)(bn * 128 + r0) * K + c0;
  const u16* Bg1 = B + (size_t)(bn * 128 + r1) * K + c1;
  u16* lA0 = &sA[lb0 >> 1];
  u16* lA1 = &sA[lb1 >> 1];
  u16* lB0 = &sB[lb0 >> 1];
  u16* lB1 = &sB[lb1 >> 1];
  f32x4 acc[4][4] = {};
  const int ra = wm + (lane & 15), rb = wn + (lane & 15), k8 = (lane >> 4) * 8;
  for (int kt = 0; kt < K; kt += 32) {
    gl16(Ag0 + kt, lA0);
    gl16(Ag1 + kt, lA1);
    gl16(Bg0 + kt, lB0);
    gl16(Bg1 + kt, lB1);
    __syncthreads();  // drains vmcnt -> tiles resident
    frag8 af[4], bf[4];
#pragma unroll
    for (int i = 0; i < 4; ++i) af[i] = *(const frag8*)&sA[(ra + i * 16) * 32 + k8];
#pragma unroll
    for (int i = 0; i < 4; ++i) bf[i] = *(const frag8*)&sB[(rb + i * 16) * 32 + k8];
#pragma unroll
    for (int i = 0; i < 4; ++i)
#pragma unroll
      for (int j = 0; j < 4; ++j) acc[i][j] = MFMA16(af[i], bf[j], acc[i][j]);
    __syncthreads();  // all reads done before next overwrite
  }
  const int cc = lane & 15, rr = (lane >> 4) * 4;
#pragma unroll
  for (int i = 0; i < 4; ++i)
#pragma unroll
    for (int j = 0; j < 4; ++j)
#pragma unroll
      for (int e = 0; e < 4; ++e) {
        int row = bm * 128 + wm + i * 16 + rr + e;
        int col = bn * 128 + wn + j * 16 + cc;
        float v = acc[i][j][e];
        if (BIAS) v += bias[col];
        C[(size_t)row * N + col] = f2bf(v);
      }
}

// ---------------------------------------------------------------- attention
// one workgroup per (window, head); 4 waves x 64 q-rows; flash-style online softmax.
// LDS 68,864 B -> 2 blocks/CU. K double-buffered per 64-key block; V^T full; P half-staged.
__global__ __launch_bounds__(256, 2) void k_attn(const u16* __restrict__ qkv,
                                                 u16* __restrict__ aout) {
  const int g = blockIdx.x;
  const int win = g >> 3, h = g & 7;
  const int tid = threadIdx.x, lane = tid & 63, wv = tid >> 6;
  __shared__ u16 Kb[2][64][68];
  __shared__ u16 Vt[64][258];
  __shared__ u16 Ps[4][64][36];
  const u16* base = qkv + (size_t)win * 256 * 1536;
  const u16* kbase = base + 512 + h * 64;
  const u16* vbase = base + 1024 + h * 64;
  const int prow = tid >> 2, pc16 = (tid & 3) * 16;

  // K block 0
  {
    const u16* kp = kbase + (size_t)prow * 1536 + pc16;
    short8 a = *(const short8*)kp;
    short8 b2 = *(const short8*)(kp + 8);
    *(short8*)&Kb[0][prow][pc16] = a;
    *(short8*)&Kb[0][prow][pc16 + 8] = b2;
  }
  // V^T (full 256 keys)
  {
    const u16* vp = vbase + (size_t)tid * 1536;
#pragma unroll
    for (int c8 = 0; c8 < 64; c8 += 8) {
      short8 v = *(const short8*)(vp + c8);
#pragma unroll
      for (int e2 = 0; e2 < 8; ++e2) Vt[c8 + e2][tid] = (u16)v[e2];
    }
  }
  // Q fragments (regs, raw — scale folded into exp)
  frag8 qf[4][2];
#pragma unroll
  for (int mf = 0; mf < 4; ++mf)
#pragma unroll
    for (int kk = 0; kk < 2; ++kk)
      qf[mf][kk] = *(const frag8*)(base + (size_t)(wv * 64 + mf * 16 + (lane & 15)) * 1536 +
                                   h * 64 + kk * 32 + (lane >> 4) * 8);
  __syncthreads();

  float m_run[4][4], l_run[4][4];
  f32x4 of[4][4];
#pragma unroll
  for (int mf = 0; mf < 4; ++mf)
#pragma unroll
    for (int j = 0; j < 4; ++j) {
      m_run[mf][j] = -3e38f;
      l_run[mf][j] = 0.f;
    }
#pragma unroll
  for (int mf = 0; mf < 4; ++mf)
#pragma unroll
    for (int df = 0; df < 4; ++df) of[mf][df] = 0.f;

  u16(*Pw)[36] = Ps[wv];
  int cur = 0;
  for (int kb = 0; kb < 4; ++kb) {
    // prefetch next K block into regs
    short8 pf0 = {}, pf1 = {};
    if (kb < 3) {
      const u16* kp = kbase + (size_t)((kb + 1) * 64 + prow) * 1536 + pc16;
      pf0 = *(const short8*)kp;
      pf1 = *(const short8*)(kp + 8);
    }
    // QK^T (raw scores)
    f32x4 sf[4][4] = {};
#pragma unroll
    for (int kk = 0; kk < 2; ++kk) {
      frag8 kf[4];
#pragma unroll
      for (int nf = 0; nf < 4; ++nf)
        kf[nf] = *(const frag8*)&Kb[cur][nf * 16 + (lane & 15)][kk * 32 + (lane >> 4) * 8];
#pragma unroll
      for (int mf = 0; mf < 4; ++mf)
#pragma unroll
        for (int nf = 0; nf < 4; ++nf) sf[mf][nf] = MFMA16(qf[mf][kk], kf[nf], sf[mf][nf]);
    }
    // online softmax (m in raw-score domain; SCALE folded into exp args; lane-local l)
#pragma unroll
    for (int mf = 0; mf < 4; ++mf) {
#pragma unroll
      for (int j = 0; j < 4; ++j) {
        float bm = fmaxf(fmaxf(sf[mf][0][j], sf[mf][1][j]), fmaxf(sf[mf][2][j], sf[mf][3][j]));
        bm = fmaxf(bm, __shfl_xor(bm, 1));
        bm = fmaxf(bm, __shfl_xor(bm, 2));
        bm = fmaxf(bm, __shfl_xor(bm, 4));
        bm = fmaxf(bm, __shfl_xor(bm, 8));
        float mo = m_run[mf][j];
        float mn = fmaxf(mo, bm);
        float corr = __expf((mo - mn) * 0.125f);
        m_run[mf][j] = mn;
        float ls = 0.f;
#pragma unroll
        for (int nf = 0; nf < 4; ++nf) {
          float p = __expf((sf[mf][nf][j] - mn) * 0.125f);
          sf[mf][nf][j] = p;
          ls += p;
        }
        l_run[mf][j] = l_run[mf][j] * corr + ls;  // lane-local partial
#pragma unroll
        for (int df = 0; df < 4; ++df) of[mf][df][j] *= corr;
      }
    }
    // PV in two kk phases (P cols kk*32..+31 staged per phase)
#pragma unroll
    for (int kk = 0; kk < 2; ++kk) {
#pragma unroll
      for (int mf = 0; mf < 4; ++mf)
#pragma unroll
        for (int nl = 0; nl < 2; ++nl) {
          int nf = kk * 2 + nl;
          int rr0 = mf * 16 + (lane >> 4) * 4;
          int c = nl * 16 + (lane & 15);
          unsigned p01 = cvtpk_bf16(sf[mf][nf][0], sf[mf][nf][1]);
          unsigned p23 = cvtpk_bf16(sf[mf][nf][2], sf[mf][nf][3]);
          Pw[rr0][c] = (u16)p01;
          Pw[rr0 + 1][c] = (u16)(p01 >> 16);
          Pw[rr0 + 2][c] = (u16)p23;
          Pw[rr0 + 3][c] = (u16)(p23 >> 16);
        }
      asm volatile("" ::: "memory");
      frag8 pa[4], vb[4];
#pragma unroll
      for (int mf = 0; mf < 4; ++mf)
        pa[mf] = *(const frag8*)&Pw[mf * 16 + (lane & 15)][(lane >> 4) * 8];
#pragma unroll
      for (int df = 0; df < 4; ++df)
        vb[df] = *(const frag8*)&Vt[df * 16 + (lane & 15)][kb * 64 + kk * 32 + (lane >> 4) * 8];
#pragma unroll
      for (int mf = 0; mf < 4; ++mf)
#pragma unroll
        for (int df = 0; df < 4; ++df) of[mf][df] = MFMA16(pa[mf], vb[df], of[mf][df]);
      asm volatile("" ::: "memory");
    }
    // write prefetched K to other buffer
    if (kb < 3) {
      *(short8*)&Kb[cur ^ 1][prow][pc16] = pf0;
      *(short8*)&Kb[cur ^ 1][prow][pc16 + 8] = pf1;
    }
    __syncthreads();
    cur ^= 1;
  }
  // epilogue: cross-lane l reduce, normalize, store
#pragma unroll
  for (int mf = 0; mf < 4; ++mf)
#pragma unroll
    for (int j = 0; j < 4; ++j) {
      float lt = l_run[mf][j];
      lt += __shfl_xor(lt, 1);
      lt += __shfl_xor(lt, 2);
      lt += __shfl_xor(lt, 4);
      lt += __shfl_xor(lt, 8);
      float inv = 1.0f / lt;
#pragma unroll
      for (int df = 0; df < 4; ++df) {
        int row = win * 256 + wv * 64 + mf * 16 + (lane >> 4) * 4 + j;
        int col = h * 64 + df * 16 + (lane & 15);
        aout[(size_t)row * 512 + col] = f2bf(of[mf][df][j] * inv);
      }
    }
}

// ---------------------------------------------------------------- finalize
__global__ void k_final(const float* __restrict__ x, const u16* __restrict__ proj,
                        const int* __restrict__ kept, const float* __restrict__ mult,
                        float* __restrict__ out) {
  const size_t idx = (size_t)blockIdx.x * 256 + threadIdx.x;
  const int dci = (int)(idx & 31);
  const int pix = (int)((idx >> 5) & 16383);
  const int b = (int)(idx >> 19);
  const int y = pix >> 7, xc = pix & 127;
  float acc[16];
#pragma unroll
  for (int e = 0; e < 16; ++e) acc[e] = 0.f;
  float c = 0.f;
  const int wyh = y >> 3, wxh = xc >> 3;
#pragma unroll
  for (int a = 0; a < 2; ++a) {
    int wy = wyh - 1 + a;
    if (wy < 0 || wy > 14) continue;
#pragma unroll
    for (int bb = 0; bb < 2; ++bb) {
      int wx = wxh - 1 + bb;
      if (wx < 0 || wx > 14) continue;
      int w = wy * 15 + wx;
      int slot = kept[b * 225 + w];
      if (slot < 0) continue;
      float ml = mult[b * 225 + w];
      c += ml;
      const u16* pr = proj +
                      ((size_t)((b * 44 + slot) * 256 + (y - wy * 8) * 16 + (xc - wx * 8))) * 512 +
                      (size_t)dci * 16;
      short8 v0 = *(const short8*)pr;
      short8 v1 = *(const short8*)(pr + 8);
#pragma unroll
      for (int e = 0; e < 8; ++e) acc[e] += ml * bf2f((u16)v0[e]);
#pragma unroll
      for (int e = 0; e < 8; ++e) acc[8 + e] += ml * bf2f((u16)v1[e]);
    }
  }
  const float inv = 1.f / (c + 1e-10f);
  const size_t off = ((size_t)(b * 16384 + pix)) * 512 + (size_t)dci * 16;
  const float4* xp = (const float4*)(x + off);
  float4* op = (float4*)(out + off);
#pragma unroll
  for (int q4 = 0; q4 < 4; ++q4) {
    float4 xv = xp[q4];
    float4 ov;
    ov.x = xv.x + acc[q4 * 4 + 0] * inv;
    ov.y = xv.y + acc[q4 * 4 + 1] * inv;
    ov.z = xv.z + acc[q4 * 4 + 2] * inv;
    ov.w = xv.w + acc[q4 * 4 + 3] * inv;
    op[q4] = ov;
  }
}

// ---------------------------------------------------------------- launch
extern "C" void kernel_launch(void* const* d_in, const int* in_sizes, int n_in, void* d_out,
                              int out_size, void* d_ws, size_t ws_size, hipStream_t stream) {
  const float* x = (const float*)d_in[0];
  const float* prob = (const float*)d_in[1];
  const float* wfix = (const float*)d_in[2];
  const float* Wq = (const float*)d_in[3];
  const float* Wo = (const float*)d_in[4];
  const float* bo = (const float*)d_in[5];
  float* out = (float*)d_out;
  char* ws = (char*)d_ws;

  float* scores = (float*)(ws + 0);
  int* sel = (int*)(ws + 8192);
  int* kept = (int*)(ws + 16384);
  float* mult = (float*)(ws + 24576);
  u16* wqb = (u16*)(ws + 32768);
  u16* wob = (u16*)(ws + 32768 + 1572864);
  u16* xi = (u16*)(ws + 4194304);
  u16* qkv = (u16*)(ws + 4194304 + 92274688);
  u16* aout = xi;
  u16* proj = qkv;

  k_score<<<8, 256, 0, stream>>>(prob, wfix, scores);
  k_nms<<<8, 256, 0, stream>>>(scores, sel, kept, mult);
  k_castw<<<4096, 256, 0, stream>>>(Wq, Wo, wqb, wob);
  k_gather<<<352, 256, 0, stream>>>(x, sel, xi);
  k_gemm<0><<<dim3(12, 704), 256, 0, stream>>>(xi, wqb, qkv, nullptr, 90112, 1536, 512);
  k_attn<<<2816, 256, 0, stream>>>(qkv, aout);
  k_gemm<1><<<dim3(4, 704), 256, 0, stream>>>(aout, wob, proj, bo, 90112, 512, 512);
  k_final<<<16384, 256, 0, stream>>>(x, proj, kept, mult, out);
}

// Round 3
// 788.967 us; speedup vs baseline: 1.2277x; 1.2005x over previous
//
#include <hip/hip_runtime.h>
#include <type_traits>
#include <utility>

typedef unsigned short u16;
typedef __attribute__((ext_vector_type(8))) short short8;
typedef __attribute__((ext_vector_type(8))) __bf16 bf16v8;
typedef __attribute__((ext_vector_type(4))) float f32x4;

template <typename T, typename = void> struct mfma_ok : std::false_type {};
template <typename T>
struct mfma_ok<T, std::void_t<decltype(__builtin_amdgcn_mfma_f32_16x16x32_bf16(
    std::declval<T>(), std::declval<T>(), std::declval<f32x4>(), 0, 0, 0))>>
    : std::true_type {};
using frag8 = std::conditional_t<mfma_ok<bf16v8>::value, bf16v8, short8>;

#define MFMA16(a, b, c) __builtin_amdgcn_mfma_f32_16x16x32_bf16((a), (b), (c), 0, 0, 0)

__device__ __forceinline__ float bf2f(u16 u) {
  unsigned v = ((unsigned)u) << 16;
  return __builtin_bit_cast(float, v);
}
__device__ __forceinline__ u16 f2bf(float f) {
  unsigned u = __builtin_bit_cast(unsigned, f);
  u = (u + 0x7fffu + ((u >> 16) & 1u)) >> 16;
  return (u16)u;
}
__device__ __forceinline__ unsigned cvtpk_bf16(float lo, float hi) {
  unsigned r;
  asm("v_cvt_pk_bf16_f32 %0, %1, %2" : "=v"(r) : "v"(lo), "v"(hi));
  return r;
}
// async global->LDS, 16B per lane; lds ptr must be wave-uniform base (+lane*16 implicit)
__device__ __forceinline__ void gl16(const u16* g, u16* l) {
  __builtin_amdgcn_global_load_lds((__attribute__((address_space(1))) void*)(g),
                                   (__attribute__((address_space(3))) void*)(l), 16, 0, 0);
}

// ---------------------------------------------------------------- score
__global__ void k_score(const float* __restrict__ prob, const float* __restrict__ wfix,
                        float* __restrict__ scores) {
  const int b = blockIdx.x, tid = threadIdx.x;
  __shared__ float ent[64 * 64];
  __shared__ float wf[64];
  if (tid < 64) wf[tid] = wfix[tid];
  const float* pb = prob + (size_t)b * 4 * 4096;
  for (int p = tid; p < 4096; p += 256) {
    float e = 0.f;
#pragma unroll
    for (int ch = 0; ch < 4; ++ch) {
      float v = pb[ch * 4096 + p];
      e -= v * log2f(v + 1e-10f);
    }
    ent[p] = e;
  }
  __syncthreads();
  if (tid < 225) {
    int wy = tid / 15, wx = tid % 15;
    float s = 0.f;
    for (int a = 0; a < 8; ++a)
      for (int c = 0; c < 8; ++c)
        s += ent[(wy * 4 + a) * 64 + wx * 4 + c] * wf[a * 8 + c];
    scores[b * 225 + tid] = s * (1.0f / 64.0f);
  }
}

// ---------------------------------------------------------------- nms
__device__ __forceinline__ float iou_pair(int wa, int wb) {
  float x1a = (float)((wa % 15) * 8), y1a = (float)((wa / 15) * 8);
  float x1b = (float)((wb % 15) * 8), y1b = (float)((wb / 15) * 8);
  float iw = fminf(x1a, x1b) + 15.f - fmaxf(x1a, x1b);
  float ih = fminf(y1a, y1b) + 15.f - fmaxf(y1a, y1b);
  iw = fmaxf(iw, 0.f);
  ih = fmaxf(ih, 0.f);
  float inter = iw * ih;
  return inter / (450.f - inter);
}

__global__ void k_nms(const float* __restrict__ scores, int* __restrict__ sel,
                      int* __restrict__ kept, float* __restrict__ mult) {
  const int b = blockIdx.x, t = threadIdx.x;
  __shared__ float s[225];
  __shared__ int order[225];
  __shared__ unsigned char supp[225];
  __shared__ int idx44[44];
  __shared__ int ks[225];
  __shared__ float ml[225];
  if (t < 225) s[t] = scores[b * 225 + t];
  __syncthreads();
  if (t < 225) {
    float st = s[t];
    int r = 0;
    for (int j = 0; j < 225; ++j) {
      float sj = s[j];
      r += (sj > st) || (sj == st && j < t);
    }
    order[r] = t;
    supp[t] = 0;
    ks[t] = -1;
    ml[t] = 0.f;
  }
  __syncthreads();
  for (int i = 0; i < 224; ++i) {
    if (t > i && t < 225 && !supp[i]) {
      if (iou_pair(order[i], order[t]) > 0.2f) supp[t] = 1;
    }
    __syncthreads();
  }
  if (t == 0) {
    int k = 0;
    for (int i = 0; i < 225 && k < 44; ++i)
      if (!supp[i]) idx44[k++] = order[i];
    while (k < 44) idx44[k++] = order[224];
    for (int k2 = 0; k2 < 44; ++k2) {
      int w = idx44[k2];
      if (ks[w] < 0) ks[w] = k2;
      ml[w] += 1.f;
    }
  }
  __syncthreads();
  if (t < 225) {
    kept[b * 225 + t] = ks[t];
    mult[b * 225 + t] = ml[t];
  }
  if (t < 44) sel[b * 44 + t] = idx44[t];
}

// ---------------------------------------------------------------- weight cast
__global__ void k_castw(const float* __restrict__ Wq, const float* __restrict__ Wo,
                        u16* __restrict__ wqb, u16* __restrict__ wob) {
  int idx = blockIdx.x * 256 + threadIdx.x;
  if (idx < 786432) wqb[idx] = f2bf(Wq[idx]);
  int i2 = idx - 786432;
  if (i2 >= 0 && i2 < 262144) wob[i2] = f2bf(Wo[i2]);
}

// ---------------------------------------------------------------- gather + bilinear (direct 4-tap)
// out[g][p*16+q][d] = w0p*(w0q*X[i0][j0][d]+w1q*X[i0][j1][d]) + w1p*(w0q*X[i1][j0][d]+w1q*X[i1][j1][d])
// lane layout: dc fastest (64 chunks of 8 dims) -> fully coalesced 2KB-row reads, 1KB writes.
__global__ __launch_bounds__(256) void k_gather(const float* __restrict__ x,
                                                const int* __restrict__ sel,
                                                u16* __restrict__ xi) {
  const size_t idx = (size_t)blockIdx.x * 256 + threadIdx.x;
  const int dc = (int)(idx & 63);
  const int pq = (int)((idx >> 6) & 255);
  const int g = (int)(idx >> 14);
  const int b = g / 44;
  const int w = sel[g];
  const int sy = (w / 15) * 8, sx = (w % 15) * 8;
  const int p = pq >> 4, q = pq & 15;
  // taps (q0+1 <= 15 always: max r = 15.5*0.9375 = 14.53)
  float rp = ((float)p + 0.5f) * 0.9375f;
  int i0 = (int)rp;
  float fp = rp - (float)i0;
  float rq = ((float)q + 0.5f) * 0.9375f;
  int j0 = (int)rq;
  float fq = rq - (float)j0;
  const float w00 = (1.f - fp) * (1.f - fq), w01 = (1.f - fp) * fq;
  const float w10 = fp * (1.f - fq), w11 = fp * fq;
  const float* xb = x + ((size_t)b * 16384 + (size_t)(sy + i0) * 128 + sx + j0) * 512 + dc * 8;
  const float4* t00 = (const float4*)xb;
  const float4* t01 = (const float4*)(xb + 512);
  const float4* t10 = (const float4*)(xb + 512 * 128);
  const float4* t11 = (const float4*)(xb + 512 * 129);
  float acc[8];
#pragma unroll
  for (int h = 0; h < 2; ++h) {
    float4 a = t00[h], bb = t01[h], c = t10[h], d = t11[h];
    acc[h * 4 + 0] = w00 * a.x + w01 * bb.x + w10 * c.x + w11 * d.x;
    acc[h * 4 + 1] = w00 * a.y + w01 * bb.y + w10 * c.y + w11 * d.y;
    acc[h * 4 + 2] = w00 * a.z + w01 * bb.z + w10 * c.z + w11 * d.z;
    acc[h * 4 + 3] = w00 * a.w + w01 * bb.w + w10 * c.w + w11 * d.w;
  }
  short8 o;
#pragma unroll
  for (int e = 0; e < 8; ++e) o[e] = (short)f2bf(acc[e]);
  *(short8*)&xi[((size_t)g * 256 + pq) * 512 + dc * 8] = o;
}

// ---------------------------------------------------------------- GEMM  C = A * B^T (+bias)
// m97 structure: global_load_lds width-16, linear LDS [128][32], 2 barriers per K-step.
template <int BIAS>
__global__ __launch_bounds__(256) void k_gemm(const u16* __restrict__ A, const u16* __restrict__ B,
                                              u16* __restrict__ C, const float* __restrict__ bias,
                                              int M, int N, int K) {
  __shared__ u16 sA[128 * 32];
  __shared__ u16 sB[128 * 32];
  const int tid = threadIdx.x, lane = tid & 63, wv = tid >> 6;
  const int bn = blockIdx.x, bm = blockIdx.y;
  const int wm = (wv >> 1) * 64, wn = (wv & 1) * 64;
  const int lb0 = wv * 2048, lb1 = wv * 2048 + 1024;
  const int gb0 = lb0 + lane * 16, gb1 = lb1 + lane * 16;
  const int r0 = gb0 >> 6, c0 = (gb0 & 63) >> 1;
  const int r1 = gb1 >> 6, c1 = (gb1 & 63) >> 1;
  const u16* Ag0 = A + (size_t)(bm * 128 + r0) * K + c0;
  const u16* Ag1 = A + (size_t)(bm * 128 + r1) * K + c1;
  const u16* Bg0 = B + (size_t)(bn * 128 + r0) * K + c0;
  const u16* Bg1 = B + (size_t)(bn * 128 + r1) * K + c1;
  u16* lA0 = &sA[lb0 >> 1];
  u16* lA1 = &sA[lb1 >> 1];
  u16* lB0 = &sB[lb0 >> 1];
  u16* lB1 = &sB[lb1 >> 1];
  f32x4 acc[4][4] = {};
  const int ra = wm + (lane & 15), rb = wn + (lane & 15), k8 = (lane >> 4) * 8;
  for (int kt = 0; kt < K; kt += 32) {
    gl16(Ag0 + kt, lA0);
    gl16(Ag1 + kt, lA1);
    gl16(Bg0 + kt, lB0);
    gl16(Bg1 + kt, lB1);
    __syncthreads();
    frag8 af[4], bf[4];
#pragma unroll
    for (int i = 0; i < 4; ++i) af[i] = *(const frag8*)&sA[(ra + i * 16) * 32 + k8];
#pragma unroll
    for (int i = 0; i < 4; ++i) bf[i] = *(const frag8*)&sB[(rb + i * 16) * 32 + k8];
#pragma unroll
    for (int i = 0; i < 4; ++i)
#pragma unroll
      for (int j = 0; j < 4; ++j) acc[i][j] = MFMA16(af[i], bf[j], acc[i][j]);
    __syncthreads();
  }
  const int cc = lane & 15, rr = (lane >> 4) * 4;
#pragma unroll
  for (int i = 0; i < 4; ++i)
#pragma unroll
    for (int j = 0; j < 4; ++j)
#pragma unroll
      for (int e = 0; e < 4; ++e) {
        int row = bm * 128 + wm + i * 16 + rr + e;
        int col = bn * 128 + wn + j * 16 + cc;
        float v = acc[i][j][e];
        if (BIAS) v += bias[col];
        C[(size_t)row * N + col] = f2bf(v);
      }
}

// ---------------------------------------------------------------- attention
__global__ __launch_bounds__(256, 2) void k_attn(const u16* __restrict__ qkv,
                                                 u16* __restrict__ aout) {
  const int g = blockIdx.x;
  const int win = g >> 3, h = g & 7;
  const int tid = threadIdx.x, lane = tid & 63, wv = tid >> 6;
  __shared__ u16 Kb[2][64][68];
  __shared__ u16 Vt[64][258];
  __shared__ u16 Ps[4][64][36];
  const u16* base = qkv + (size_t)win * 256 * 1536;
  const u16* kbase = base + 512 + h * 64;
  const u16* vbase = base + 1024 + h * 64;
  const int prow = tid >> 2, pc16 = (tid & 3) * 16;

  {
    const u16* kp = kbase + (size_t)prow * 1536 + pc16;
    short8 a = *(const short8*)kp;
    short8 b2 = *(const short8*)(kp + 8);
    *(short8*)&Kb[0][prow][pc16] = a;
    *(short8*)&Kb[0][prow][pc16 + 8] = b2;
  }
  {
    const u16* vp = vbase + (size_t)tid * 1536;
#pragma unroll
    for (int c8 = 0; c8 < 64; c8 += 8) {
      short8 v = *(const short8*)(vp + c8);
#pragma unroll
      for (int e2 = 0; e2 < 8; ++e2) Vt[c8 + e2][tid] = (u16)v[e2];
    }
  }
  frag8 qf[4][2];
#pragma unroll
  for (int mf = 0; mf < 4; ++mf)
#pragma unroll
    for (int kk = 0; kk < 2; ++kk)
      qf[mf][kk] = *(const frag8*)(base + (size_t)(wv * 64 + mf * 16 + (lane & 15)) * 1536 +
                                   h * 64 + kk * 32 + (lane >> 4) * 8);
  __syncthreads();

  float m_run[4][4], l_run[4][4];
  f32x4 of[4][4];
#pragma unroll
  for (int mf = 0; mf < 4; ++mf)
#pragma unroll
    for (int j = 0; j < 4; ++j) {
      m_run[mf][j] = -3e38f;
      l_run[mf][j] = 0.f;
    }
#pragma unroll
  for (int mf = 0; mf < 4; ++mf)
#pragma unroll
    for (int df = 0; df < 4; ++df) of[mf][df] = 0.f;

  u16(*Pw)[36] = Ps[wv];
  int cur = 0;
  for (int kb = 0; kb < 4; ++kb) {
    short8 pf0 = {}, pf1 = {};
    if (kb < 3) {
      const u16* kp = kbase + (size_t)((kb + 1) * 64 + prow) * 1536 + pc16;
      pf0 = *(const short8*)kp;
      pf1 = *(const short8*)(kp + 8);
    }
    f32x4 sf[4][4] = {};
#pragma unroll
    for (int kk = 0; kk < 2; ++kk) {
      frag8 kf[4];
#pragma unroll
      for (int nf = 0; nf < 4; ++nf)
        kf[nf] = *(const frag8*)&Kb[cur][nf * 16 + (lane & 15)][kk * 32 + (lane >> 4) * 8];
#pragma unroll
      for (int mf = 0; mf < 4; ++mf)
#pragma unroll
        for (int nf = 0; nf < 4; ++nf) sf[mf][nf] = MFMA16(qf[mf][kk], kf[nf], sf[mf][nf]);
    }
#pragma unroll
    for (int mf = 0; mf < 4; ++mf) {
#pragma unroll
      for (int j = 0; j < 4; ++j) {
        float bm = fmaxf(fmaxf(sf[mf][0][j], sf[mf][1][j]), fmaxf(sf[mf][2][j], sf[mf][3][j]));
        bm = fmaxf(bm, __shfl_xor(bm, 1));
        bm = fmaxf(bm, __shfl_xor(bm, 2));
        bm = fmaxf(bm, __shfl_xor(bm, 4));
        bm = fmaxf(bm, __shfl_xor(bm, 8));
        float mo = m_run[mf][j];
        float mn = fmaxf(mo, bm);
        float corr = __expf((mo - mn) * 0.125f);
        m_run[mf][j] = mn;
        float ls = 0.f;
#pragma unroll
        for (int nf = 0; nf < 4; ++nf) {
          float p = __expf((sf[mf][nf][j] - mn) * 0.125f);
          sf[mf][nf][j] = p;
          ls += p;
        }
        l_run[mf][j] = l_run[mf][j] * corr + ls;
#pragma unroll
        for (int df = 0; df < 4; ++df) of[mf][df][j] *= corr;
      }
    }
#pragma unroll
    for (int kk = 0; kk < 2; ++kk) {
#pragma unroll
      for (int mf = 0; mf < 4; ++mf)
#pragma unroll
        for (int nl = 0; nl < 2; ++nl) {
          int nf = kk * 2 + nl;
          int rr0 = mf * 16 + (lane >> 4) * 4;
          int c = nl * 16 + (lane & 15);
          unsigned p01 = cvtpk_bf16(sf[mf][nf][0], sf[mf][nf][1]);
          unsigned p23 = cvtpk_bf16(sf[mf][nf][2], sf[mf][nf][3]);
          Pw[rr0][c] = (u16)p01;
          Pw[rr0 + 1][c] = (u16)(p01 >> 16);
          Pw[rr0 + 2][c] = (u16)p23;
          Pw[rr0 + 3][c] = (u16)(p23 >> 16);
        }
      asm volatile("" ::: "memory");
      frag8 pa[4], vb[4];
#pragma unroll
      for (int mf = 0; mf < 4; ++mf)
        pa[mf] = *(const frag8*)&Pw[mf * 16 + (lane & 15)][(lane >> 4) * 8];
#pragma unroll
      for (int df = 0; df < 4; ++df)
        vb[df] = *(const frag8*)&Vt[df * 16 + (lane & 15)][kb * 64 + kk * 32 + (lane >> 4) * 8];
#pragma unroll
      for (int mf = 0; mf < 4; ++mf)
#pragma unroll
        for (int df = 0; df < 4; ++df) of[mf][df] = MFMA16(pa[mf], vb[df], of[mf][df]);
      asm volatile("" ::: "memory");
    }
    if (kb < 3) {
      *(short8*)&Kb[cur ^ 1][prow][pc16] = pf0;
      *(short8*)&Kb[cur ^ 1][prow][pc16 + 8] = pf1;
    }
    __syncthreads();
    cur ^= 1;
  }
#pragma unroll
  for (int mf = 0; mf < 4; ++mf)
#pragma unroll
    for (int j = 0; j < 4; ++j) {
      float lt = l_run[mf][j];
      lt += __shfl_xor(lt, 1);
      lt += __shfl_xor(lt, 2);
      lt += __shfl_xor(lt, 4);
      lt += __shfl_xor(lt, 8);
      float inv = 1.0f / lt;
#pragma unroll
      for (int df = 0; df < 4; ++df) {
        int row = win * 256 + wv * 64 + mf * 16 + (lane >> 4) * 4 + j;
        int col = h * 64 + df * 16 + (lane & 15);
        aout[(size_t)row * 512 + col] = f2bf(of[mf][df][j] * inv);
      }
    }
}

// ---------------------------------------------------------------- finalize
__global__ void k_final(const float* __restrict__ x, const u16* __restrict__ proj,
                        const int* __restrict__ kept, const float* __restrict__ mult,
                        float* __restrict__ out) {
  const size_t idx = (size_t)blockIdx.x * 256 + threadIdx.x;
  const int dci = (int)(idx & 31);
  const int pix = (int)((idx >> 5) & 16383);
  const int b = (int)(idx >> 19);
  const int y = pix >> 7, xc = pix & 127;
  float acc[16];
#pragma unroll
  for (int e = 0; e < 16; ++e) acc[e] = 0.f;
  float c = 0.f;
  const int wyh = y >> 3, wxh = xc >> 3;
#pragma unroll
  for (int a = 0; a < 2; ++a) {
    int wy = wyh - 1 + a;
    if (wy < 0 || wy > 14) continue;
#pragma unroll
    for (int bb = 0; bb < 2; ++bb) {
      int wx = wxh - 1 + bb;
      if (wx < 0 || wx > 14) continue;
      int w = wy * 15 + wx;
      int slot = kept[b * 225 + w];
      if (slot < 0) continue;
      float ml = mult[b * 225 + w];
      c += ml;
      const u16* pr = proj +
                      ((size_t)((b * 44 + slot) * 256 + (y - wy * 8) * 16 + (xc - wx * 8))) * 512 +
                      (size_t)dci * 16;
      short8 v0 = *(const short8*)pr;
      short8 v1 = *(const short8*)(pr + 8);
#pragma unroll
      for (int e = 0; e < 8; ++e) acc[e] += ml * bf2f((u16)v0[e]);
#pragma unroll
      for (int e = 0; e < 8; ++e) acc[8 + e] += ml * bf2f((u16)v1[e]);
    }
  }
  const float inv = 1.f / (c + 1e-10f);
  const size_t off = ((size_t)(b * 16384 + pix)) * 512 + (size_t)dci * 16;
  const float4* xp = (const float4*)(x + off);
  float4* op = (float4*)(out + off);
#pragma unroll
  for (int q4 = 0; q4 < 4; ++q4) {
    float4 xv = xp[q4];
    float4 ov;
    ov.x = xv.x + acc[q4 * 4 + 0] * inv;
    ov.y = xv.y + acc[q4 * 4 + 1] * inv;
    ov.z = xv.z + acc[q4 * 4 + 2] * inv;
    ov.w = xv.w + acc[q4 * 4 + 3] * inv;
    op[q4] = ov;
  }
}

// ---------------------------------------------------------------- launch
extern "C" void kernel_launch(void* const* d_in, const int* in_sizes, int n_in, void* d_out,
                              int out_size, void* d_ws, size_t ws_size, hipStream_t stream) {
  const float* x = (const float*)d_in[0];
  const float* prob = (const float*)d_in[1];
  const float* wfix = (const float*)d_in[2];
  const float* Wq = (const float*)d_in[3];
  const float* Wo = (const float*)d_in[4];
  const float* bo = (const float*)d_in[5];
  float* out = (float*)d_out;
  char* ws = (char*)d_ws;

  float* scores = (float*)(ws + 0);
  int* sel = (int*)(ws + 8192);
  int* kept = (int*)(ws + 16384);
  float* mult = (float*)(ws + 24576);
  u16* wqb = (u16*)(ws + 32768);
  u16* wob = (u16*)(ws + 32768 + 1572864);
  u16* xi = (u16*)(ws + 4194304);
  u16* qkv = (u16*)(ws + 4194304 + 92274688);
  u16* aout = xi;
  u16* proj = qkv;

  k_score<<<8, 256, 0, stream>>>(prob, wfix, scores);
  k_nms<<<8, 256, 0, stream>>>(scores, sel, kept, mult);
  k_castw<<<4096, 256, 0, stream>>>(Wq, Wo, wqb, wob);
  k_gather<<<22528, 256, 0, stream>>>(x, sel, xi);
  k_gemm<0><<<dim3(12, 704), 256, 0, stream>>>(xi, wqb, qkv, nullptr, 90112, 1536, 512);
  k_attn<<<2816, 256, 0, stream>>>(qkv, aout);
  k_gemm<1><<<dim3(4, 704), 256, 0, stream>>>(aout, wob, proj, bo, 90112, 512, 512);
  k_final<<<16384, 256, 0, stream>>>(x, proj, kept, mult, out);
}

// Round 4
// 766.535 us; speedup vs baseline: 1.2637x; 1.0293x over previous
//
#include <hip/hip_runtime.h>
#include <type_traits>
#include <utility>

typedef unsigned short u16;
typedef __attribute__((ext_vector_type(8))) short short8;
typedef __attribute__((ext_vector_type(8))) __bf16 bf16v8;
typedef __attribute__((ext_vector_type(4))) float f32x4;
typedef __attribute__((ext_vector_type(16))) float f32x16;

template <typename T, typename = void> struct mfma_ok : std::false_type {};
template <typename T>
struct mfma_ok<T, std::void_t<decltype(__builtin_amdgcn_mfma_f32_16x16x32_bf16(
    std::declval<T>(), std::declval<T>(), std::declval<f32x4>(), 0, 0, 0))>>
    : std::true_type {};
using frag8 = std::conditional_t<mfma_ok<bf16v8>::value, bf16v8, short8>;

#define MFMA16(a, b, c) __builtin_amdgcn_mfma_f32_16x16x32_bf16((a), (b), (c), 0, 0, 0)
#define MFMA32(a, b, c) __builtin_amdgcn_mfma_f32_32x32x16_bf16((a), (b), (c), 0, 0, 0)

__device__ __forceinline__ float bf2f(u16 u) {
  unsigned v = ((unsigned)u) << 16;
  return __builtin_bit_cast(float, v);
}
__device__ __forceinline__ u16 f2bf(float f) {
  unsigned u = __builtin_bit_cast(unsigned, f);
  u = (u + 0x7fffu + ((u >> 16) & 1u)) >> 16;
  return (u16)u;
}
__device__ __forceinline__ unsigned cvtpk_bf16(float lo, float hi) {
  unsigned r;
  asm("v_cvt_pk_bf16_f32 %0, %1, %2" : "=v"(r) : "v"(lo), "v"(hi));
  return r;
}
// async global->LDS, 16B per lane; lds ptr must be wave-uniform base (+lane*16 implicit)
__device__ __forceinline__ void gl16(const u16* g, u16* l) {
  __builtin_amdgcn_global_load_lds((__attribute__((address_space(1))) void*)(g),
                                   (__attribute__((address_space(3))) void*)(l), 16, 0, 0);
}

// ---------------------------------------------------------------- score
__global__ void k_score(const float* __restrict__ prob, const float* __restrict__ wfix,
                        float* __restrict__ scores) {
  const int b = blockIdx.x, tid = threadIdx.x;
  __shared__ float ent[64 * 64];
  __shared__ float wf[64];
  if (tid < 64) wf[tid] = wfix[tid];
  const float* pb = prob + (size_t)b * 4 * 4096;
  for (int p = tid; p < 4096; p += 256) {
    float e = 0.f;
#pragma unroll
    for (int ch = 0; ch < 4; ++ch) {
      float v = pb[ch * 4096 + p];
      e -= v * log2f(v + 1e-10f);
    }
    ent[p] = e;
  }
  __syncthreads();
  if (tid < 225) {
    int wy = tid / 15, wx = tid % 15;
    float s = 0.f;
    for (int a = 0; a < 8; ++a)
      for (int c = 0; c < 8; ++c)
        s += ent[(wy * 4 + a) * 64 + wx * 4 + c] * wf[a * 8 + c];
    scores[b * 225 + tid] = s * (1.0f / 64.0f);
  }
}

// ---------------------------------------------------------------- nms
__device__ __forceinline__ float iou_pair(int wa, int wb) {
  float x1a = (float)((wa % 15) * 8), y1a = (float)((wa / 15) * 8);
  float x1b = (float)((wb % 15) * 8), y1b = (float)((wb / 15) * 8);
  float iw = fminf(x1a, x1b) + 15.f - fmaxf(x1a, x1b);
  float ih = fminf(y1a, y1b) + 15.f - fmaxf(y1a, y1b);
  iw = fmaxf(iw, 0.f);
  ih = fmaxf(ih, 0.f);
  float inter = iw * ih;
  return inter / (450.f - inter);
}

__global__ void k_nms(const float* __restrict__ scores, int* __restrict__ sel,
                      int* __restrict__ kept, float* __restrict__ mult) {
  const int b = blockIdx.x, t = threadIdx.x;
  __shared__ float s[225];
  __shared__ int order[225];
  __shared__ unsigned char supp[225];
  __shared__ int idx44[44];
  __shared__ int ks[225];
  __shared__ float ml[225];
  if (t < 225) s[t] = scores[b * 225 + t];
  __syncthreads();
  if (t < 225) {
    float st = s[t];
    int r = 0;
    for (int j = 0; j < 225; ++j) {
      float sj = s[j];
      r += (sj > st) || (sj == st && j < t);
    }
    order[r] = t;
    supp[t] = 0;
    ks[t] = -1;
    ml[t] = 0.f;
  }
  __syncthreads();
  for (int i = 0; i < 224; ++i) {
    if (t > i && t < 225 && !supp[i]) {
      if (iou_pair(order[i], order[t]) > 0.2f) supp[t] = 1;
    }
    __syncthreads();
  }
  if (t == 0) {
    int k = 0;
    for (int i = 0; i < 225 && k < 44; ++i)
      if (!supp[i]) idx44[k++] = order[i];
    while (k < 44) idx44[k++] = order[224];
    for (int k2 = 0; k2 < 44; ++k2) {
      int w = idx44[k2];
      if (ks[w] < 0) ks[w] = k2;
      ml[w] += 1.f;
    }
  }
  __syncthreads();
  if (t < 225) {
    kept[b * 225 + t] = ks[t];
    mult[b * 225 + t] = ml[t];
  }
  if (t < 44) sel[b * 44 + t] = idx44[t];
}

// ---------------------------------------------------------------- weight cast
__global__ void k_castw(const float* __restrict__ Wq, const float* __restrict__ Wo,
                        u16* __restrict__ wqb, u16* __restrict__ wob) {
  int idx = blockIdx.x * 256 + threadIdx.x;
  if (idx < 786432) wqb[idx] = f2bf(Wq[idx]);
  int i2 = idx - 786432;
  if (i2 >= 0 && i2 < 262144) wob[i2] = f2bf(Wo[i2]);
}

// ---------------------------------------------------------------- gather + bilinear (direct 4-tap)
__global__ __launch_bounds__(256) void k_gather(const float* __restrict__ x,
                                                const int* __restrict__ sel,
                                                u16* __restrict__ xi) {
  const size_t idx = (size_t)blockIdx.x * 256 + threadIdx.x;
  const int dc = (int)(idx & 63);
  const int pq = (int)((idx >> 6) & 255);
  const int g = (int)(idx >> 14);
  const int b = g / 44;
  const int w = sel[g];
  const int sy = (w / 15) * 8, sx = (w % 15) * 8;
  const int p = pq >> 4, q = pq & 15;
  float rp = ((float)p + 0.5f) * 0.9375f;
  int i0 = (int)rp;
  float fp = rp - (float)i0;
  float rq = ((float)q + 0.5f) * 0.9375f;
  int j0 = (int)rq;
  float fq = rq - (float)j0;
  const float w00 = (1.f - fp) * (1.f - fq), w01 = (1.f - fp) * fq;
  const float w10 = fp * (1.f - fq), w11 = fp * fq;
  const float* xb = x + ((size_t)b * 16384 + (size_t)(sy + i0) * 128 + sx + j0) * 512 + dc * 8;
  const float4* t00 = (const float4*)xb;
  const float4* t01 = (const float4*)(xb + 512);
  const float4* t10 = (const float4*)(xb + 512 * 128);
  const float4* t11 = (const float4*)(xb + 512 * 129);
  float acc[8];
#pragma unroll
  for (int h = 0; h < 2; ++h) {
    float4 a = t00[h], bb = t01[h], c = t10[h], d = t11[h];
    acc[h * 4 + 0] = w00 * a.x + w01 * bb.x + w10 * c.x + w11 * d.x;
    acc[h * 4 + 1] = w00 * a.y + w01 * bb.y + w10 * c.y + w11 * d.y;
    acc[h * 4 + 2] = w00 * a.z + w01 * bb.z + w10 * c.z + w11 * d.z;
    acc[h * 4 + 3] = w00 * a.w + w01 * bb.w + w10 * c.w + w11 * d.w;
  }
  short8 o;
#pragma unroll
  for (int e = 0; e < 8; ++e) o[e] = (short)f2bf(acc[e]);
  *(short8*)&xi[((size_t)g * 256 + pq) * 512 + dc * 8] = o;
}

// ---------------------------------------------------------------- GEMM  C = A * B^T (+bias)
template <int BIAS>
__global__ __launch_bounds__(256) void k_gemm(const u16* __restrict__ A, const u16* __restrict__ B,
                                              u16* __restrict__ C, const float* __restrict__ bias,
                                              int M, int N, int K) {
  __shared__ u16 sA[128 * 32];
  __shared__ u16 sB[128 * 32];
  const int tid = threadIdx.x, lane = tid & 63, wv = tid >> 6;
  const int bn = blockIdx.x, bm = blockIdx.y;
  const int wm = (wv >> 1) * 64, wn = (wv & 1) * 64;
  const int lb0 = wv * 2048, lb1 = wv * 2048 + 1024;
  const int gb0 = lb0 + lane * 16, gb1 = lb1 + lane * 16;
  const int r0 = gb0 >> 6, c0 = (gb0 & 63) >> 1;
  const int r1 = gb1 >> 6, c1 = (gb1 & 63) >> 1;
  const u16* Ag0 = A + (size_t)(bm * 128 + r0) * K + c0;
  const u16* Ag1 = A + (size_t)(bm * 128 + r1) * K + c1;
  const u16* Bg0 = B + (size_t)(bn * 128 + r0) * K + c0;
  const u16* Bg1 = B + (size_t)(bn * 128 + r1) * K + c1;
  u16* lA0 = &sA[lb0 >> 1];
  u16* lA1 = &sA[lb1 >> 1];
  u16* lB0 = &sB[lb0 >> 1];
  u16* lB1 = &sB[lb1 >> 1];
  f32x4 acc[4][4] = {};
  const int ra = wm + (lane & 15), rb = wn + (lane & 15), k8 = (lane >> 4) * 8;
  for (int kt = 0; kt < K; kt += 32) {
    gl16(Ag0 + kt, lA0);
    gl16(Ag1 + kt, lA1);
    gl16(Bg0 + kt, lB0);
    gl16(Bg1 + kt, lB1);
    __syncthreads();
    frag8 af[4], bf[4];
#pragma unroll
    for (int i = 0; i < 4; ++i) af[i] = *(const frag8*)&sA[(ra + i * 16) * 32 + k8];
#pragma unroll
    for (int i = 0; i < 4; ++i) bf[i] = *(const frag8*)&sB[(rb + i * 16) * 32 + k8];
#pragma unroll
    for (int i = 0; i < 4; ++i)
#pragma unroll
      for (int j = 0; j < 4; ++j) acc[i][j] = MFMA16(af[i], bf[j], acc[i][j]);
    __syncthreads();
  }
  const int cc = lane & 15, rr = (lane >> 4) * 4;
#pragma unroll
  for (int i = 0; i < 4; ++i)
#pragma unroll
    for (int j = 0; j < 4; ++j)
#pragma unroll
      for (int e = 0; e < 4; ++e) {
        int row = bm * 128 + wm + i * 16 + rr + e;
        int col = bn * 128 + wn + j * 16 + cc;
        float v = acc[i][j][e];
        if (BIAS) v += bias[col];
        C[(size_t)row * N + col] = f2bf(v);
      }
}

// ---------------------------------------------------------------- attention (swapped 32x32)
// One block per (win, head); 4 waves x 64 q-rows (2 q-tiles of 32).
// QK^T computed as S^T = mfma32(K, Q^T): col=lane&31=q -> each lane owns ONE q.
// PV computed as O^T = mfma32(V^T, P^T): col=q -> m/l/corr/normalize all lane-local.
// P^T B-frags built in-register via cvt_pk + shfl_xor(32) (no P LDS).
__global__ __launch_bounds__(256, 2) void k_attn(const u16* __restrict__ qkv,
                                                 u16* __restrict__ aout) {
  const int g = blockIdx.x;
  const int win = g >> 3, h = g & 7;
  const int tid = threadIdx.x, lane = tid & 63, wv = tid >> 6;
  const int l31 = lane & 31, l5 = lane >> 5;
  const bool lo32 = (lane < 32);
  __shared__ u16 smem[25344];  // Kb[2][64][68] (8704) | Vt[64][260] (16640)
  u16* KbB = smem;
  u16* VtB = smem + 8704;
  const u16* base = qkv + (size_t)win * 256 * 1536;
  const u16* kbase = base + 512 + h * 64;
  const u16* vbase = base + 1024 + h * 64;
  const int prow = tid >> 2, pc16 = (tid & 3) * 16;

  // stage K block 0
  {
    const u16* kp = kbase + (size_t)prow * 1536 + pc16;
    *(short8*)&KbB[prow * 68 + pc16] = *(const short8*)kp;
    *(short8*)&KbB[prow * 68 + pc16 + 8] = *(const short8*)(kp + 8);
  }
  // stage V^T: Vt[d][key] (thread tid owns key=tid)
  {
    const u16* vp = vbase + (size_t)tid * 1536;
#pragma unroll
    for (int c8 = 0; c8 < 64; c8 += 8) {
      short8 v = *(const short8*)(vp + c8);
#pragma unroll
      for (int e2 = 0; e2 < 8; ++e2) VtB[(c8 + e2) * 260 + tid] = (u16)v[e2];
    }
  }
  // Q B-frags: lane holds Q[q=qt*32+l31][c*16 + l5*8 .. +7]
  frag8 qf[2][4];
#pragma unroll
  for (int qt = 0; qt < 2; ++qt)
#pragma unroll
    for (int c = 0; c < 4; ++c)
      qf[qt][c] = *(const frag8*)(base + (size_t)(wv * 64 + qt * 32 + l31) * 1536 + h * 64 +
                                  c * 16 + l5 * 8);
  __syncthreads();

  f32x16 of[2][2] = {};  // [qt][dt], O^T tile: row=d (reg-map), col=q=l31
  float m_run[2] = {-3e38f, -3e38f};
  float l_run[2] = {0.f, 0.f};

  int cur = 0;
  for (int kb = 0; kb < 4; ++kb) {
    short8 pf0 = {}, pf1 = {};
    if (kb < 3) {
      const u16* kp = kbase + (size_t)((kb + 1) * 64 + prow) * 1536 + pc16;
      pf0 = *(const short8*)kp;
      pf1 = *(const short8*)(kp + 8);
    }
#pragma unroll
    for (int qt = 0; qt < 2; ++qt) {
      // S^T[key][q] for 64 keys x 32 q
      f32x16 s0 = {}, s1 = {};
#pragma unroll
      for (int c = 0; c < 4; ++c) {
        frag8 kf0 = *(const frag8*)&KbB[cur * 4352 + l31 * 68 + c * 16 + l5 * 8];
        frag8 kf1 = *(const frag8*)&KbB[cur * 4352 + (32 + l31) * 68 + c * 16 + l5 * 8];
        s0 = MFMA32(kf0, qf[qt][c], s0);
        s1 = MFMA32(kf1, qf[qt][c], s1);
      }
      // lane-local max over 32 keys + one cross-half shfl
      float tm[16];
#pragma unroll
      for (int r = 0; r < 16; ++r) tm[r] = fmaxf(s0[r], s1[r]);
#pragma unroll
      for (int r = 0; r < 8; ++r) tm[r] = fmaxf(tm[r], tm[r + 8]);
#pragma unroll
      for (int r = 0; r < 4; ++r) tm[r] = fmaxf(tm[r], tm[r + 4]);
      float pm = fmaxf(fmaxf(tm[0], tm[1]), fmaxf(tm[2], tm[3]));
      pm = fmaxf(pm, __shfl_xor(pm, 32));
      // defer-max: only rescale when max grew beyond threshold (8 post-scale = 64 raw)
      if (!__all(pm <= m_run[qt] + 64.f)) {
        float mn = fmaxf(m_run[qt], pm);
        float corr = __expf((m_run[qt] - mn) * 0.125f);
        l_run[qt] *= corr;
#pragma unroll
        for (int dt = 0; dt < 2; ++dt)
#pragma unroll
          for (int r = 0; r < 16; ++r) of[qt][dt][r] *= corr;
        m_run[qt] = mn;
      }
      const float mqt = m_run[qt];
      float ls = 0.f;
#pragma unroll
      for (int kt = 0; kt < 2; ++kt) {
        const f32x16 sv = kt ? s1 : s0;
        float p[16];
#pragma unroll
        for (int r = 0; r < 16; ++r) p[r] = __expf((sv[r] - mqt) * 0.125f);
        float e0 = (p[0] + p[1]) + (p[2] + p[3]);
        float e1 = (p[4] + p[5]) + (p[6] + p[7]);
        float e2 = (p[8] + p[9]) + (p[10] + p[11]);
        float e3 = (p[12] + p[13]) + (p[14] + p[15]);
        ls += (e0 + e1) + (e2 + e3);
        // P^T B-frags + PV
#pragma unroll
        for (int cc = 0; cc < 2; ++cc) {
          const int bx = cc * 8;
          unsigned a0 = cvtpk_bf16(p[bx + 0], p[bx + 1]);
          unsigned a1 = cvtpk_bf16(p[bx + 2], p[bx + 3]);
          unsigned b0 = cvtpk_bf16(p[bx + 4], p[bx + 5]);
          unsigned b1 = cvtpk_bf16(p[bx + 6], p[bx + 7]);
          unsigned sa0 = __shfl_xor(a0, 32);
          unsigned sa1 = __shfl_xor(a1, 32);
          unsigned sb0 = __shfl_xor(b0, 32);
          unsigned sb1 = __shfl_xor(b1, 32);
          uint4 fu;
          fu.x = lo32 ? a0 : sb0;
          fu.y = lo32 ? a1 : sb1;
          fu.z = lo32 ? sa0 : b0;
          fu.w = lo32 ? sa1 : b1;
          frag8 pb = __builtin_bit_cast(frag8, fu);
#pragma unroll
          for (int dt = 0; dt < 2; ++dt) {
            frag8 va = *(const frag8*)&VtB[(dt * 32 + l31) * 260 + kb * 64 + kt * 32 + cc * 16 +
                                           l5 * 8];
            of[qt][dt] = MFMA32(va, pb, of[qt][dt]);
          }
        }
      }
      l_run[qt] += ls;
    }
    if (kb < 3) {
      *(short8*)&KbB[(cur ^ 1) * 4352 + prow * 68 + pc16] = pf0;
      *(short8*)&KbB[(cur ^ 1) * 4352 + prow * 68 + pc16 + 8] = pf1;
    }
    __syncthreads();
    cur ^= 1;
  }

  // epilogue: normalize (lane-local), transpose via reused LDS, coalesced stores
  float inv[2];
#pragma unroll
  for (int qt = 0; qt < 2; ++qt) {
    float lt = l_run[qt] + __shfl_xor(l_run[qt], 32);
    inv[qt] = 1.0f / lt;
  }
  u16* sc = smem + wv * 4352;  // per-wave [64][68]
#pragma unroll
  for (int qt = 0; qt < 2; ++qt)
#pragma unroll
    for (int dt = 0; dt < 2; ++dt)
#pragma unroll
      for (int j = 0; j < 4; ++j) {
        unsigned w0 = cvtpk_bf16(of[qt][dt][4 * j + 0] * inv[qt], of[qt][dt][4 * j + 1] * inv[qt]);
        unsigned w1 = cvtpk_bf16(of[qt][dt][4 * j + 2] * inv[qt], of[qt][dt][4 * j + 3] * inv[qt]);
        *(uint2*)&sc[(qt * 32 + l31) * 68 + dt * 32 + 8 * j + 4 * l5] = make_uint2(w0, w1);
      }
  __syncthreads();
#pragma unroll
  for (int rep = 0; rep < 8; ++rep) {
    int row = rep * 8 + (lane >> 3);
    uint2 lo = *(const uint2*)&sc[row * 68 + (lane & 7) * 8];
    uint2 hi = *(const uint2*)&sc[row * 68 + (lane & 7) * 8 + 4];
    *(int4*)&aout[(size_t)(win * 256 + wv * 64 + row) * 512 + h * 64 + (lane & 7) * 8] =
        make_int4((int)lo.x, (int)lo.y, (int)hi.x, (int)hi.y);
  }
}

// ---------------------------------------------------------------- finalize
__global__ void k_final(const float* __restrict__ x, const u16* __restrict__ proj,
                        const int* __restrict__ kept, const float* __restrict__ mult,
                        float* __restrict__ out) {
  const size_t idx = (size_t)blockIdx.x * 256 + threadIdx.x;
  const int dci = (int)(idx & 31);
  const int pix = (int)((idx >> 5) & 16383);
  const int b = (int)(idx >> 19);
  const int y = pix >> 7, xc = pix & 127;
  float acc[16];
#pragma unroll
  for (int e = 0; e < 16; ++e) acc[e] = 0.f;
  float c = 0.f;
  const int wyh = y >> 3, wxh = xc >> 3;
#pragma unroll
  for (int a = 0; a < 2; ++a) {
    int wy = wyh - 1 + a;
    if (wy < 0 || wy > 14) continue;
#pragma unroll
    for (int bb = 0; bb < 2; ++bb) {
      int wx = wxh - 1 + bb;
      if (wx < 0 || wx > 14) continue;
      int w = wy * 15 + wx;
      int slot = kept[b * 225 + w];
      if (slot < 0) continue;
      float ml = mult[b * 225 + w];
      c += ml;
      const u16* pr = proj +
                      ((size_t)((b * 44 + slot) * 256 + (y - wy * 8) * 16 + (xc - wx * 8))) * 512 +
                      (size_t)dci * 16;
      short8 v0 = *(const short8*)pr;
      short8 v1 = *(const short8*)(pr + 8);
#pragma unroll
      for (int e = 0; e < 8; ++e) acc[e] += ml * bf2f((u16)v0[e]);
#pragma unroll
      for (int e = 0; e < 8; ++e) acc[8 + e] += ml * bf2f((u16)v1[e]);
    }
  }
  const float inv = 1.f / (c + 1e-10f);
  const size_t off = ((size_t)(b * 16384 + pix)) * 512 + (size_t)dci * 16;
  const float4* xp = (const float4*)(x + off);
  float4* op = (float4*)(out + off);
#pragma unroll
  for (int q4 = 0; q4 < 4; ++q4) {
    float4 xv = xp[q4];
    float4 ov;
    ov.x = xv.x + acc[q4 * 4 + 0] * inv;
    ov.y = xv.y + acc[q4 * 4 + 1] * inv;
    ov.z = xv.z + acc[q4 * 4 + 2] * inv;
    ov.w = xv.w + acc[q4 * 4 + 3] * inv;
    op[q4] = ov;
  }
}

// ---------------------------------------------------------------- launch
extern "C" void kernel_launch(void* const* d_in, const int* in_sizes, int n_in, void* d_out,
                              int out_size, void* d_ws, size_t ws_size, hipStream_t stream) {
  const float* x = (const float*)d_in[0];
  const float* prob = (const float*)d_in[1];
  const float* wfix = (const float*)d_in[2];
  const float* Wq = (const float*)d_in[3];
  const float* Wo = (const float*)d_in[4];
  const float* bo = (const float*)d_in[5];
  float* out = (float*)d_out;
  char* ws = (char*)d_ws;

  float* scores = (float*)(ws + 0);
  int* sel = (int*)(ws + 8192);
  int* kept = (int*)(ws + 16384);
  float* mult = (float*)(ws + 24576);
  u16* wqb = (u16*)(ws + 32768);
  u16* wob = (u16*)(ws + 32768 + 1572864);
  u16* xi = (u16*)(ws + 4194304);
  u16* qkv = (u16*)(ws + 4194304 + 92274688);
  u16* aout = xi;
  u16* proj = qkv;

  k_score<<<8, 256, 0, stream>>>(prob, wfix, scores);
  k_nms<<<8, 256, 0, stream>>>(scores, sel, kept, mult);
  k_castw<<<4096, 256, 0, stream>>>(Wq, Wo, wqb, wob);
  k_gather<<<22528, 256, 0, stream>>>(x, sel, xi);
  k_gemm<0><<<dim3(12, 704), 256, 0, stream>>>(xi, wqb, qkv, nullptr, 90112, 1536, 512);
  k_attn<<<2816, 256, 0, stream>>>(qkv, aout);
  k_gemm<1><<<dim3(4, 704), 256, 0, stream>>>(aout, wob, proj, bo, 90112, 512, 512);
  k_final<<<16384, 256, 0, stream>>>(x, proj, kept, mult, out);
}